// Round 4
// baseline (2238.376 us; speedup 1.0000x reference)
//
#include <hip/hip_runtime.h>

#define BB 64
#define MM 512
#define NN 512
#define NUM_SINK 20
#define SLICES 8   // workgroups per batch (persistent path)

// base-2 domain: exp(x) == exp2(x*log2e); K2 = log2(e)/lambda
constexpr float NEG_K2 = -(1.4426950408889634f / 0.002f);   // ~ -721.3475

__device__ __forceinline__ float exp2fast(float x) { return __builtin_amdgcn_exp2f(x); }
__device__ __forceinline__ float log2fast(float x) { return __builtin_amdgcn_logf(x); }

// 8-WG per-batch barrier: release fence -> arrive -> spin -> acquire fence.
// Monotone target, counters zeroed by a memset node each launch.
__device__ __forceinline__ void batch_barrier(unsigned* ctr, unsigned target) {
    __syncthreads();
    if (threadIdx.x == 0) {
        __threadfence();
        __hip_atomic_fetch_add(ctr, 1u, __ATOMIC_RELAXED, __HIP_MEMORY_SCOPE_AGENT);
        while (__hip_atomic_load(ctr, __ATOMIC_ACQUIRE, __HIP_MEMORY_SCOPE_AGENT) < target)
            __builtin_amdgcn_s_sleep(2);
        __threadfence();
    }
    __syncthreads();
}

// max over the 512 per-thread values; trailing barrier protects sRed reuse
__device__ __forceinline__ float block_max512(float v, float* sRed) {
    const int t = threadIdx.x;
    float wm = v;
    #pragma unroll
    for (int o = 32; o > 0; o >>= 1) wm = fmaxf(wm, __shfl_xor(wm, o, 64));
    if ((t & 63) == 0) sRed[t >> 6] = wm;
    __syncthreads();
    if (t == 0) {
        float m2 = sRed[0];
        #pragma unroll
        for (int i = 1; i < 8; ++i) m2 = fmaxf(m2, sRed[i]);
        sRed[0] = m2;
    }
    __syncthreads();
    const float r = sRed[0];
    __syncthreads();
    return r;
}

// ============================================================================
// Persistent path: plain launch, 512 WGs x 512 thr, __launch_bounds__(512,4)
// -> 2 blocks/CU x 256 CU = 512: entire grid co-resident (guide §1 pattern).
// wg%8 = XCD (round-robin dispatch) so each batch's 8 WGs cluster per-XCD L2.
// ============================================================================
__global__ __launch_bounds__(512, 4) void sink_kernel(
    const float* __restrict__ c, const float* __restrict__ amarg,
    const float* __restrict__ bmarg, float* __restrict__ out,
    float* __restrict__ F, float* __restrict__ G, unsigned* __restrict__ ctr)
{
    __shared__ float sV[NN];            // F' (col phase) / G' (row phase), <= 0
    __shared__ float sPart[32][64];     // col-phase partial sums
    __shared__ float sRed[8];

    const int wg    = blockIdx.x;
    const int b     = (wg & 7) * 8 + (wg >> 6);   // XCD-clustered batch
    const int slice = (wg >> 3) & 7;              // 0..7 within batch
    const int t     = threadIdx.x;
    const float* cb = c + (size_t)b * MM * NN;
    unsigned* bc    = ctr + b;
    unsigned target = 0;

    const int n0   = slice * 64;        // col-phase column range
    const int m0   = slice * 64;        // row-phase row range
    const int tx   = t & 15;
    const int ty   = t >> 4;
    const int wave = t >> 6;
    const int lane = t & 63;

    for (int it = 0; it < NUM_SINK; ++it) {
        // ===== column phase: G[b][n] = log2 b_n - maxF - log2 sum_m exp2(F'_m - c*K2)
        float maxF = 0.f, fv = 0.f;
        if (it != 0) {
            fv   = F[b * MM + t];
            maxF = block_max512(fv, sRed);
        }
        sV[t] = fv - maxF;
        __syncthreads();

        float s0 = 0.f, s1 = 0.f, s2 = 0.f, s3 = 0.f;
        const float* p0 = cb + (size_t)(ty * 16) * NN + n0 + tx * 4;
        #pragma unroll 4
        for (int r = 0; r < 16; ++r) {
            const float  fp = sV[ty * 16 + r];
            const float4 cv = *(const float4*)(p0 + (size_t)r * NN);
            s0 += exp2fast(fmaf(cv.x, NEG_K2, fp));
            s1 += exp2fast(fmaf(cv.y, NEG_K2, fp));
            s2 += exp2fast(fmaf(cv.z, NEG_K2, fp));
            s3 += exp2fast(fmaf(cv.w, NEG_K2, fp));
        }
        sPart[ty][tx * 4 + 0] = s0;
        sPart[ty][tx * 4 + 1] = s1;
        sPart[ty][tx * 4 + 2] = s2;
        sPart[ty][tx * 4 + 3] = s3;
        __syncthreads();
        if (t < 64) {
            float tot = 0.f;
            #pragma unroll
            for (int g = 0; g < 32; ++g) tot += sPart[g][t];
            const int n = n0 + t;
            G[b * NN + n] = log2fast(bmarg[b * NN + n]) - maxF - log2fast(tot);
        }
        target += SLICES;
        batch_barrier(bc, target);

        // ===== row phase: F[b][m] = log2 a_m - maxG - log2 sum_n exp2(G'_n - c*K2)
        const float gv   = G[b * NN + t];
        const float maxG = block_max512(gv, sRed);
        sV[t] = gv - maxG;
        __syncthreads();

        const float4 g0 = *(const float4*)&sV[lane * 4];
        const float4 g1 = *(const float4*)&sV[lane * 4 + 256];
        const bool last = (it == NUM_SINK - 1);

        #pragma unroll 2
        for (int r = 0; r < 8; ++r) {
            const int m = m0 + wave * 8 + r;
            const float* rowp = cb + (size_t)m * NN;
            const float4 c0 = *(const float4*)(rowp + lane * 4);
            const float4 c1 = *(const float4*)(rowp + lane * 4 + 256);

            float s = exp2fast(fmaf(c0.x, NEG_K2, g0.x)) + exp2fast(fmaf(c0.y, NEG_K2, g0.y))
                    + exp2fast(fmaf(c0.z, NEG_K2, g0.z)) + exp2fast(fmaf(c0.w, NEG_K2, g0.w))
                    + exp2fast(fmaf(c1.x, NEG_K2, g1.x)) + exp2fast(fmaf(c1.y, NEG_K2, g1.y))
                    + exp2fast(fmaf(c1.z, NEG_K2, g1.z)) + exp2fast(fmaf(c1.w, NEG_K2, g1.w));
            #pragma unroll
            for (int o = 32; o > 0; o >>= 1) s += __shfl_xor(s, o, 64);

            const float Fm = log2fast(amarg[b * MM + m]) - maxG - log2fast(s);
            if (lane == 0) F[b * MM + m] = Fm;

            if (last) {   // fused output: p = exp2(Fm + maxG + G'_n - c*K2)
                const float base = Fm + maxG;
                float4 o0, o1;
                o0.x = exp2fast(fmaf(c0.x, NEG_K2, base + g0.x));
                o0.y = exp2fast(fmaf(c0.y, NEG_K2, base + g0.y));
                o0.z = exp2fast(fmaf(c0.z, NEG_K2, base + g0.z));
                o0.w = exp2fast(fmaf(c0.w, NEG_K2, base + g0.w));
                o1.x = exp2fast(fmaf(c1.x, NEG_K2, base + g1.x));
                o1.y = exp2fast(fmaf(c1.y, NEG_K2, base + g1.y));
                o1.z = exp2fast(fmaf(c1.z, NEG_K2, base + g1.z));
                o1.w = exp2fast(fmaf(c1.w, NEG_K2, base + g1.w));
                float* op = out + (size_t)b * MM * NN + (size_t)m * NN;
                *(float4*)(op + lane * 4)       = o0;
                *(float4*)(op + lane * 4 + 256) = o1;
            }
        }
        if (!last) {
            target += SLICES;
            batch_barrier(bc, target);
        }
    }
}

// ============================================================================
// Fallback path (known-correct round-1 kernels): used only if ws_size is too
// small for the barrier counters. 40 dispatches.
// ============================================================================
__global__ __launch_bounds__(512) void col_kernel(
    const float* __restrict__ c, const float* __restrict__ bmarg,
    const float* __restrict__ F, float* __restrict__ G, int first)
{
    __shared__ float sF[MM];
    __shared__ float sPart[16][128];
    __shared__ float sRed[8];

    const int b  = blockIdx.x >> 2;
    const int n0 = (blockIdx.x & 3) * 128;
    const int t  = threadIdx.x;

    float maxF = 0.0f, v = 0.0f;
    if (!first) {
        v = F[b * MM + t];
        maxF = block_max512(v, sRed);
    }
    sF[t] = v - maxF;
    __syncthreads();

    const int lane_c = t & 31;
    const int mg     = t >> 5;
    const int n4     = n0 + lane_c * 4;
    const float* cp  = c + (size_t)b * MM * NN;
    const int m0     = mg * 32;

    float s0 = 0.f, s1 = 0.f, s2 = 0.f, s3 = 0.f;
    #pragma unroll 4
    for (int r = 0; r < 32; ++r) {
        const int m = m0 + r;
        const float fp = sF[m];
        const float4 cv = *(const float4*)(cp + (size_t)m * NN + n4);
        s0 += exp2fast(fmaf(cv.x, NEG_K2, fp));
        s1 += exp2fast(fmaf(cv.y, NEG_K2, fp));
        s2 += exp2fast(fmaf(cv.z, NEG_K2, fp));
        s3 += exp2fast(fmaf(cv.w, NEG_K2, fp));
    }
    sPart[mg][lane_c * 4 + 0] = s0;
    sPart[mg][lane_c * 4 + 1] = s1;
    sPart[mg][lane_c * 4 + 2] = s2;
    sPart[mg][lane_c * 4 + 3] = s3;
    __syncthreads();

    if (t < 128) {
        float tot = 0.f;
        #pragma unroll
        for (int g = 0; g < 16; ++g) tot += sPart[g][t];
        const int n = n0 + t;
        G[b * NN + n] = log2fast(bmarg[b * NN + n]) - maxF - log2fast(tot);
    }
}

template <bool WRITE_OUT>
__global__ __launch_bounds__(512) void row_kernel(
    const float* __restrict__ c, const float* __restrict__ amarg,
    const float* __restrict__ G, float* __restrict__ F, float* __restrict__ out)
{
    __shared__ float sG[NN];
    __shared__ float sRed[8];

    const int b  = blockIdx.x >> 3;
    const int m0 = (blockIdx.x & 7) * 64;
    const int t  = threadIdx.x;

    const float v    = G[b * NN + t];
    const float maxG = block_max512(v, sRed);
    sG[t] = v - maxG;
    __syncthreads();

    const int wave = t >> 6;
    const int lane = t & 63;
    const float* cp = c + (size_t)b * MM * NN;

    const float4 g0 = *(const float4*)&sG[lane * 4];
    const float4 g1 = *(const float4*)&sG[lane * 4 + 256];

    #pragma unroll 2
    for (int r = 0; r < 8; ++r) {
        const int m = m0 + wave * 8 + r;
        const float* rowp = cp + (size_t)m * NN;
        const float4 c0 = *(const float4*)(rowp + lane * 4);
        const float4 c1 = *(const float4*)(rowp + lane * 4 + 256);

        float s = exp2fast(fmaf(c0.x, NEG_K2, g0.x)) + exp2fast(fmaf(c0.y, NEG_K2, g0.y))
                + exp2fast(fmaf(c0.z, NEG_K2, g0.z)) + exp2fast(fmaf(c0.w, NEG_K2, g0.w))
                + exp2fast(fmaf(c1.x, NEG_K2, g1.x)) + exp2fast(fmaf(c1.y, NEG_K2, g1.y))
                + exp2fast(fmaf(c1.z, NEG_K2, g1.z)) + exp2fast(fmaf(c1.w, NEG_K2, g1.w));
        #pragma unroll
        for (int o = 32; o > 0; o >>= 1) s += __shfl_xor(s, o, 64);

        const float Fm = log2fast(amarg[b * MM + m]) - maxG - log2fast(s);
        if (lane == 0) F[b * MM + m] = Fm;

        if (WRITE_OUT) {
            const float base = Fm + maxG;
            float4 o0, o1;
            o0.x = exp2fast(fmaf(c0.x, NEG_K2, base + g0.x));
            o0.y = exp2fast(fmaf(c0.y, NEG_K2, base + g0.y));
            o0.z = exp2fast(fmaf(c0.z, NEG_K2, base + g0.z));
            o0.w = exp2fast(fmaf(c0.w, NEG_K2, base + g0.w));
            o1.x = exp2fast(fmaf(c1.x, NEG_K2, base + g1.x));
            o1.y = exp2fast(fmaf(c1.y, NEG_K2, base + g1.y));
            o1.z = exp2fast(fmaf(c1.z, NEG_K2, base + g1.z));
            o1.w = exp2fast(fmaf(c1.w, NEG_K2, base + g1.w));
            float* op = out + (size_t)b * MM * NN + (size_t)m * NN;
            *(float4*)(op + lane * 4)       = o0;
            *(float4*)(op + lane * 4 + 256) = o1;
        }
    }
}

extern "C" void kernel_launch(void* const* d_in, const int* in_sizes, int n_in,
                              void* d_out, int out_size, void* d_ws, size_t ws_size,
                              hipStream_t stream) {
    const float* c  = (const float*)d_in[0];
    const float* am = (const float*)d_in[1];
    const float* bm = (const float*)d_in[2];
    float* out = (float*)d_out;

    float*    F   = (float*)d_ws;                 // [BB][MM]  128 KB
    float*    G   = F + BB * MM;                  // [BB][NN]  128 KB
    unsigned* ctr = (unsigned*)(G + BB * NN);     // [BB]      256 B

    const size_t need = (size_t)(BB * MM + BB * NN) * sizeof(float)
                      + (size_t)BB * sizeof(unsigned);

    if (ws_size >= need) {
        // persistent path: zero the monotone barrier counters, then one launch
        hipMemsetAsync(ctr, 0, BB * sizeof(unsigned), stream);
        hipLaunchKernelGGL(sink_kernel, dim3(BB * SLICES), dim3(512), 0, stream,
                           c, am, bm, out, F, G, ctr);
    } else {
        // fallback: 40-dispatch known-correct path (needs only F+G in ws)
        for (int it = 0; it < NUM_SINK; ++it) {
            hipLaunchKernelGGL(col_kernel, dim3(BB * 4), dim3(512), 0, stream,
                               c, bm, F, G, it == 0 ? 1 : 0);
            if (it < NUM_SINK - 1)
                hipLaunchKernelGGL(row_kernel<false>, dim3(BB * 8), dim3(512), 0, stream,
                                   c, am, G, F, out);
            else
                hipLaunchKernelGGL(row_kernel<true>, dim3(BB * 8), dim3(512), 0, stream,
                                   c, am, G, F, out);
        }
    }
}

// Round 6
// 957.340 us; speedup vs baseline: 2.3381x; 2.3381x over previous
//
#include <hip/hip_runtime.h>

#define BB 64
#define MM 512
#define NN 512
#define NUM_SINK 20
#define SLICES 8   // workgroups per batch (persistent path)

// base-2 domain: exp(x) == exp2(x*log2e); K2 = log2(e)/lambda
constexpr float NEG_K2 = -(1.4426950408889634f / 0.002f);   // ~ -721.3475

__device__ __forceinline__ float exp2fast(float x) { return __builtin_amdgcn_exp2f(x); }
__device__ __forceinline__ float log2fast(float x) { return __builtin_amdgcn_logf(x); }

// coherent per-access helpers: lower to sc-flagged global ops (bypass stale
// L1/L2), served at the device coherence point. NO cache-wide maintenance.
__device__ __forceinline__ float ld_coh(const float* p) {
    return __hip_atomic_load(p, __ATOMIC_RELAXED, __HIP_MEMORY_SCOPE_AGENT);
}
__device__ __forceinline__ void st_coh(float* p, float v) {
    __hip_atomic_store(p, v, __ATOMIC_RELAXED, __HIP_MEMORY_SCOPE_AGENT);
}

// 8-WG per-batch barrier. All waves' flagged stores are already drained by the
// compiler's s_waitcnt vmcnt(0) before s_barrier (__syncthreads semantics);
// thread 0 re-drains its own, arrives with a RELAXED add, spins RELAXED.
// No fences -> no L2 invalidate storm (that was the 2286us bug).
__device__ __forceinline__ void batch_barrier(unsigned* ctr, unsigned target) {
    __syncthreads();
    if (threadIdx.x == 0) {
        asm volatile("s_waitcnt vmcnt(0)" ::: "memory");
        __hip_atomic_fetch_add(ctr, 1u, __ATOMIC_RELAXED, __HIP_MEMORY_SCOPE_AGENT);
        while (__hip_atomic_load(ctr, __ATOMIC_RELAXED, __HIP_MEMORY_SCOPE_AGENT) < target)
            __builtin_amdgcn_s_sleep(2);
    }
    __syncthreads();
}

// max over the 512 per-thread values; trailing barrier protects sRed reuse
__device__ __forceinline__ float block_max512(float v, float* sRed) {
    const int t = threadIdx.x;
    float wm = v;
    #pragma unroll
    for (int o = 32; o > 0; o >>= 1) wm = fmaxf(wm, __shfl_xor(wm, o, 64));
    if ((t & 63) == 0) sRed[t >> 6] = wm;
    __syncthreads();
    if (t == 0) {
        float m2 = sRed[0];
        #pragma unroll
        for (int i = 1; i < 8; ++i) m2 = fmaxf(m2, sRed[i]);
        sRed[0] = m2;
    }
    __syncthreads();
    const float r = sRed[0];
    __syncthreads();
    return r;
}

// ============================================================================
// Persistent path: plain launch, 512 WGs x 512 thr, __launch_bounds__(512,4)
// -> 2 blocks/CU x 256 CU = 512: entire grid co-resident (guide §1 pattern).
// wg%8 = XCD (round-robin dispatch) so each batch's 8 WGs cluster per-XCD L2.
// ============================================================================
__global__ __launch_bounds__(512, 4) void sink_kernel(
    const float* __restrict__ c, const float* __restrict__ amarg,
    const float* __restrict__ bmarg, float* __restrict__ out,
    float* __restrict__ F, float* __restrict__ G, unsigned* __restrict__ ctr)
{
    __shared__ float sV[NN];            // F' (col phase) / G' (row phase), <= 0
    __shared__ float sPart[32][64];     // col-phase partial sums
    __shared__ float sRed[8];

    const int wg    = blockIdx.x;
    const int b     = (wg & 7) * 8 + (wg >> 6);   // XCD-clustered batch
    const int slice = (wg >> 3) & 7;              // 0..7 within batch
    const int t     = threadIdx.x;
    const float* cb = c + (size_t)b * MM * NN;
    unsigned* bc    = ctr + b;
    unsigned target = 0;

    const int n0   = slice * 64;        // col-phase column range
    const int m0   = slice * 64;        // row-phase row range
    const int tx   = t & 15;
    const int ty   = t >> 4;
    const int wave = t >> 6;
    const int lane = t & 63;

    for (int it = 0; it < NUM_SINK; ++it) {
        // ===== column phase: G[b][n] = log2 b_n - maxF - log2 sum_m exp2(F'_m - c*K2)
        float maxF = 0.f, fv = 0.f;
        if (it != 0) {
            fv   = ld_coh(&F[b * MM + t]);
            maxF = block_max512(fv, sRed);
        }
        sV[t] = fv - maxF;
        __syncthreads();

        float s0 = 0.f, s1 = 0.f, s2 = 0.f, s3 = 0.f;
        const float* p0 = cb + (size_t)(ty * 16) * NN + n0 + tx * 4;
        #pragma unroll 4
        for (int r = 0; r < 16; ++r) {
            const float  fp = sV[ty * 16 + r];
            const float4 cv = *(const float4*)(p0 + (size_t)r * NN);
            s0 += exp2fast(fmaf(cv.x, NEG_K2, fp));
            s1 += exp2fast(fmaf(cv.y, NEG_K2, fp));
            s2 += exp2fast(fmaf(cv.z, NEG_K2, fp));
            s3 += exp2fast(fmaf(cv.w, NEG_K2, fp));
        }
        sPart[ty][tx * 4 + 0] = s0;
        sPart[ty][tx * 4 + 1] = s1;
        sPart[ty][tx * 4 + 2] = s2;
        sPart[ty][tx * 4 + 3] = s3;
        __syncthreads();
        if (t < 64) {
            float tot = 0.f;
            #pragma unroll
            for (int g = 0; g < 32; ++g) tot += sPart[g][t];
            const int n = n0 + t;
            st_coh(&G[b * NN + n],
                   log2fast(bmarg[b * NN + n]) - maxF - log2fast(tot));
        }
        target += SLICES;
        batch_barrier(bc, target);

        // ===== row phase: F[b][m] = log2 a_m - maxG - log2 sum_n exp2(G'_n - c*K2)
        const float gv   = ld_coh(&G[b * NN + t]);
        const float maxG = block_max512(gv, sRed);
        sV[t] = gv - maxG;
        __syncthreads();

        const float4 g0 = *(const float4*)&sV[lane * 4];
        const float4 g1 = *(const float4*)&sV[lane * 4 + 256];
        const bool last = (it == NUM_SINK - 1);

        #pragma unroll 2
        for (int r = 0; r < 8; ++r) {
            const int m = m0 + wave * 8 + r;
            const float* rowp = cb + (size_t)m * NN;
            const float4 c0 = *(const float4*)(rowp + lane * 4);
            const float4 c1 = *(const float4*)(rowp + lane * 4 + 256);

            float s = exp2fast(fmaf(c0.x, NEG_K2, g0.x)) + exp2fast(fmaf(c0.y, NEG_K2, g0.y))
                    + exp2fast(fmaf(c0.z, NEG_K2, g0.z)) + exp2fast(fmaf(c0.w, NEG_K2, g0.w))
                    + exp2fast(fmaf(c1.x, NEG_K2, g1.x)) + exp2fast(fmaf(c1.y, NEG_K2, g1.y))
                    + exp2fast(fmaf(c1.z, NEG_K2, g1.z)) + exp2fast(fmaf(c1.w, NEG_K2, g1.w));
            #pragma unroll
            for (int o = 32; o > 0; o >>= 1) s += __shfl_xor(s, o, 64);

            const float Fm = log2fast(amarg[b * MM + m]) - maxG - log2fast(s);
            if (lane == 0) st_coh(&F[b * MM + m], Fm);

            if (last) {   // fused output: p = exp2(Fm + maxG + G'_n - c*K2)
                const float base = Fm + maxG;
                float4 o0, o1;
                o0.x = exp2fast(fmaf(c0.x, NEG_K2, base + g0.x));
                o0.y = exp2fast(fmaf(c0.y, NEG_K2, base + g0.y));
                o0.z = exp2fast(fmaf(c0.z, NEG_K2, base + g0.z));
                o0.w = exp2fast(fmaf(c0.w, NEG_K2, base + g0.w));
                o1.x = exp2fast(fmaf(c1.x, NEG_K2, base + g1.x));
                o1.y = exp2fast(fmaf(c1.y, NEG_K2, base + g1.y));
                o1.z = exp2fast(fmaf(c1.z, NEG_K2, base + g1.z));
                o1.w = exp2fast(fmaf(c1.w, NEG_K2, base + g1.w));
                float* op = out + (size_t)b * MM * NN + (size_t)m * NN;
                *(float4*)(op + lane * 4)       = o0;
                *(float4*)(op + lane * 4 + 256) = o1;
            }
        }
        if (!last) {
            target += SLICES;
            batch_barrier(bc, target);
        }
    }
}

// ============================================================================
// Fallback path (known-correct round-1 kernels): used only if ws_size is too
// small for the barrier counters. 40 dispatches.
// ============================================================================
__global__ __launch_bounds__(512) void col_kernel(
    const float* __restrict__ c, const float* __restrict__ bmarg,
    const float* __restrict__ F, float* __restrict__ G, int first)
{
    __shared__ float sF[MM];
    __shared__ float sPart[16][128];
    __shared__ float sRed[8];

    const int b  = blockIdx.x >> 2;
    const int n0 = (blockIdx.x & 3) * 128;
    const int t  = threadIdx.x;

    float maxF = 0.0f, v = 0.0f;
    if (!first) {
        v = F[b * MM + t];
        maxF = block_max512(v, sRed);
    }
    sF[t] = v - maxF;
    __syncthreads();

    const int lane_c = t & 31;
    const int mg     = t >> 5;
    const int n4     = n0 + lane_c * 4;
    const float* cp  = c + (size_t)b * MM * NN;
    const int m0     = mg * 32;

    float s0 = 0.f, s1 = 0.f, s2 = 0.f, s3 = 0.f;
    #pragma unroll 4
    for (int r = 0; r < 32; ++r) {
        const int m = m0 + r;
        const float fp = sF[m];
        const float4 cv = *(const float4*)(cp + (size_t)m * NN + n4);
        s0 += exp2fast(fmaf(cv.x, NEG_K2, fp));
        s1 += exp2fast(fmaf(cv.y, NEG_K2, fp));
        s2 += exp2fast(fmaf(cv.z, NEG_K2, fp));
        s3 += exp2fast(fmaf(cv.w, NEG_K2, fp));
    }
    sPart[mg][lane_c * 4 + 0] = s0;
    sPart[mg][lane_c * 4 + 1] = s1;
    sPart[mg][lane_c * 4 + 2] = s2;
    sPart[mg][lane_c * 4 + 3] = s3;
    __syncthreads();

    if (t < 128) {
        float tot = 0.f;
        #pragma unroll
        for (int g = 0; g < 16; ++g) tot += sPart[g][t];
        const int n = n0 + t;
        G[b * NN + n] = log2fast(bmarg[b * NN + n]) - maxF - log2fast(tot);
    }
}

template <bool WRITE_OUT>
__global__ __launch_bounds__(512) void row_kernel(
    const float* __restrict__ c, const float* __restrict__ amarg,
    const float* __restrict__ G, float* __restrict__ F, float* __restrict__ out)
{
    __shared__ float sG[NN];
    __shared__ float sRed[8];

    const int b  = blockIdx.x >> 3;
    const int m0 = (blockIdx.x & 7) * 64;
    const int t  = threadIdx.x;

    const float v    = G[b * NN + t];
    const float maxG = block_max512(v, sRed);
    sG[t] = v - maxG;
    __syncthreads();

    const int wave = t >> 6;
    const int lane = t & 63;
    const float* cp = c + (size_t)b * MM * NN;

    const float4 g0 = *(const float4*)&sG[lane * 4];
    const float4 g1 = *(const float4*)&sG[lane * 4 + 256];

    #pragma unroll 2
    for (int r = 0; r < 8; ++r) {
        const int m = m0 + wave * 8 + r;
        const float* rowp = cp + (size_t)m * NN;
        const float4 c0 = *(const float4*)(rowp + lane * 4);
        const float4 c1 = *(const float4*)(rowp + lane * 4 + 256);

        float s = exp2fast(fmaf(c0.x, NEG_K2, g0.x)) + exp2fast(fmaf(c0.y, NEG_K2, g0.y))
                + exp2fast(fmaf(c0.z, NEG_K2, g0.z)) + exp2fast(fmaf(c0.w, NEG_K2, g0.w))
                + exp2fast(fmaf(c1.x, NEG_K2, g1.x)) + exp2fast(fmaf(c1.y, NEG_K2, g1.y))
                + exp2fast(fmaf(c1.z, NEG_K2, g1.z)) + exp2fast(fmaf(c1.w, NEG_K2, g1.w));
        #pragma unroll
        for (int o = 32; o > 0; o >>= 1) s += __shfl_xor(s, o, 64);

        const float Fm = log2fast(amarg[b * MM + m]) - maxG - log2fast(s);
        if (lane == 0) F[b * MM + m] = Fm;

        if (WRITE_OUT) {
            const float base = Fm + maxG;
            float4 o0, o1;
            o0.x = exp2fast(fmaf(c0.x, NEG_K2, base + g0.x));
            o0.y = exp2fast(fmaf(c0.y, NEG_K2, base + g0.y));
            o0.z = exp2fast(fmaf(c0.z, NEG_K2, base + g0.z));
            o0.w = exp2fast(fmaf(c0.w, NEG_K2, base + g0.w));
            o1.x = exp2fast(fmaf(c1.x, NEG_K2, base + g1.x));
            o1.y = exp2fast(fmaf(c1.y, NEG_K2, base + g1.y));
            o1.z = exp2fast(fmaf(c1.z, NEG_K2, base + g1.z));
            o1.w = exp2fast(fmaf(c1.w, NEG_K2, base + g1.w));
            float* op = out + (size_t)b * MM * NN + (size_t)m * NN;
            *(float4*)(op + lane * 4)       = o0;
            *(float4*)(op + lane * 4 + 256) = o1;
        }
    }
}

extern "C" void kernel_launch(void* const* d_in, const int* in_sizes, int n_in,
                              void* d_out, int out_size, void* d_ws, size_t ws_size,
                              hipStream_t stream) {
    const float* c  = (const float*)d_in[0];
    const float* am = (const float*)d_in[1];
    const float* bm = (const float*)d_in[2];
    float* out = (float*)d_out;

    float*    F   = (float*)d_ws;                 // [BB][MM]  128 KB
    float*    G   = F + BB * MM;                  // [BB][NN]  128 KB
    unsigned* ctr = (unsigned*)(G + BB * NN);     // [BB]      256 B

    const size_t need = (size_t)(BB * MM + BB * NN) * sizeof(float)
                      + (size_t)BB * sizeof(unsigned);

    if (ws_size >= need) {
        // persistent path: zero the monotone barrier counters, then one launch
        hipMemsetAsync(ctr, 0, BB * sizeof(unsigned), stream);
        hipLaunchKernelGGL(sink_kernel, dim3(BB * SLICES), dim3(512), 0, stream,
                           c, am, bm, out, F, G, ctr);
    } else {
        // fallback: 40-dispatch known-correct path (needs only F+G in ws)
        for (int it = 0; it < NUM_SINK; ++it) {
            hipLaunchKernelGGL(col_kernel, dim3(BB * 4), dim3(512), 0, stream,
                               c, bm, F, G, it == 0 ? 1 : 0);
            if (it < NUM_SINK - 1)
                hipLaunchKernelGGL(row_kernel<false>, dim3(BB * 8), dim3(512), 0, stream,
                                   c, am, G, F, out);
            else
                hipLaunchKernelGGL(row_kernel<true>, dim3(BB * 8), dim3(512), 0, stream,
                                   c, am, G, F, out);
        }
    }
}

// Round 9
// 358.282 us; speedup vs baseline: 6.2475x; 2.6720x over previous
//
#include <hip/hip_runtime.h>

#define BB 64
#define MM 512
#define NN 512
#define NUM_SINK 20
#define SLICES 8   // workgroups per batch (persistent path)

// base-2 domain: exp(x) == exp2(x*log2e); K2 = log2(e)/lambda
constexpr float NEG_K2 = -(1.4426950408889634f / 0.002f);   // ~ -721.3475

__device__ __forceinline__ float exp2fast(float x) { return __builtin_amdgcn_exp2f(x); }
__device__ __forceinline__ float log2fast(float x) { return __builtin_amdgcn_logf(x); }
__device__ __forceinline__ float rcpfast(float x)  { return __builtin_amdgcn_rcpf(x); }

// coherent per-access helpers: sc-flagged global ops, no cache-wide maintenance
__device__ __forceinline__ float ld_coh(const float* p) {
    return __hip_atomic_load(p, __ATOMIC_RELAXED, __HIP_MEMORY_SCOPE_AGENT);
}
__device__ __forceinline__ void st_coh(float* p, float v) {
    __hip_atomic_store(p, v, __ATOMIC_RELAXED, __HIP_MEMORY_SCOPE_AGENT);
}

// 8-WG per-batch barrier (R6-proven). s_sleep(8) lowers poll traffic.
__device__ __forceinline__ void batch_barrier(unsigned* ctr, unsigned target) {
    __syncthreads();
    if (threadIdx.x == 0) {
        asm volatile("s_waitcnt vmcnt(0)" ::: "memory");
        __hip_atomic_fetch_add(ctr, 1u, __ATOMIC_RELAXED, __HIP_MEMORY_SCOPE_AGENT);
        while (__hip_atomic_load(ctr, __ATOMIC_RELAXED, __HIP_MEMORY_SCOPE_AGENT) < target)
            __builtin_amdgcn_s_sleep(8);
    }
    __syncthreads();
}

// ============================================================================
// Fused persistent kernel: 512 WGs x 512 thr, 2 WG/CU co-resident.
// WG owns a fixed 64-row stripe of its batch. Per iteration, ONE sweep of the
// stripe computes: row sums -> F_m (implicit, as a_m/s) -> next col partials
//   colPartNext[n] += exp2(F_m - cK2) = (a_m/s) * e_n * exp2(-g_n),
// where e_n = exp2(g_n - cK2) is reused from the row-sum. 1 exp2/elem/iter.
// One barrier per iteration; G rebuilt redundantly per-WG from colPart.
// ============================================================================
__global__ __launch_bounds__(512, 4) void sink_fused(
    const float* __restrict__ c, const float* __restrict__ amarg,
    const float* __restrict__ bmarg, float* __restrict__ out,
    float* __restrict__ colPart, unsigned* __restrict__ ctr)
{
    __shared__ float sPartial[SLICES][NN];  // 16 KB: per-wave col partials
    __shared__ float sG[NN];                //  2 KB

    const int wg    = blockIdx.x;
    const int b     = (wg & 7) * 8 + (wg >> 6);   // XCD-clustered batch
    const int slice = (wg >> 3) & 7;
    const int t     = threadIdx.x;
    const int wave  = t >> 6;
    const int lane  = t & 63;

    const float* cb = c + (size_t)b * MM * NN;
    float*   cpB    = colPart + (size_t)b * SLICES * NN;   // [slice][n]
    unsigned* bc    = ctr + b;

    const int m0 = slice * 64;                       // stripe rows [m0, m0+64)
    const float* wrow = cb + (size_t)(m0 + wave * 8) * NN + lane * 4;
    const float  lbT  = log2fast(bmarg[b * NN + t]); // log2 b for column t

    // ---- presweep (F = 0): colPart[slice][n] = sum_{m in stripe} exp2(-cK2)
    {
        float4 ca0 = {0.f,0.f,0.f,0.f}, ca1 = {0.f,0.f,0.f,0.f};
        #pragma unroll
        for (int r = 0; r < 8; ++r) {
            const float4 c0 = *(const float4*)(wrow + (size_t)r * NN);
            const float4 c1 = *(const float4*)(wrow + (size_t)r * NN + 256);
            ca0.x += exp2fast(c0.x * NEG_K2);  ca0.y += exp2fast(c0.y * NEG_K2);
            ca0.z += exp2fast(c0.z * NEG_K2);  ca0.w += exp2fast(c0.w * NEG_K2);
            ca1.x += exp2fast(c1.x * NEG_K2);  ca1.y += exp2fast(c1.y * NEG_K2);
            ca1.z += exp2fast(c1.z * NEG_K2);  ca1.w += exp2fast(c1.w * NEG_K2);
        }
        *(float4*)&sPartial[wave][lane * 4]       = ca0;
        *(float4*)&sPartial[wave][lane * 4 + 256] = ca1;
        __syncthreads();
        float p8 = 0.f;
        #pragma unroll
        for (int w = 0; w < SLICES; ++w) p8 += sPartial[w][t];
        st_coh(&cpB[slice * NN + t], p8);
    }
    unsigned target = SLICES;
    batch_barrier(bc, target);

    // ---- 20 fused iterations
    for (int it = 1; it <= NUM_SINK; ++it) {
        // G-reduce (redundant per WG): G_t = log2 b_t - log2 sum_s colPart[s][t]
        float s8 = 0.f;
        #pragma unroll
        for (int w = 0; w < SLICES; ++w) s8 += ld_coh(&cpB[w * NN + t]);
        sG[t] = lbT - log2fast(s8);
        __syncthreads();

        const float4 g0 = *(const float4*)&sG[lane * 4];
        const float4 g1 = *(const float4*)&sG[lane * 4 + 256];
        const bool lastIt = (it == NUM_SINK);

        float4 iv0, iv1;                       // exp2(-g), only for colAcc
        if (!lastIt) {
            iv0.x = exp2fast(-g0.x); iv0.y = exp2fast(-g0.y);
            iv0.z = exp2fast(-g0.z); iv0.w = exp2fast(-g0.w);
            iv1.x = exp2fast(-g1.x); iv1.y = exp2fast(-g1.y);
            iv1.z = exp2fast(-g1.z); iv1.w = exp2fast(-g1.w);
        }

        float4 ca0 = {0.f,0.f,0.f,0.f}, ca1 = {0.f,0.f,0.f,0.f};
        float4 cc0 = *(const float4*)(wrow);
        float4 cc1 = *(const float4*)(wrow + 256);

        #pragma unroll
        for (int r = 0; r < 8; ++r) {
            float4 cn0 = cc0, cn1 = cc1;
            if (r < 7) {                       // prefetch next row
                cn0 = *(const float4*)(wrow + (size_t)(r + 1) * NN);
                cn1 = *(const float4*)(wrow + (size_t)(r + 1) * NN + 256);
            }
            float4 e0, e1;                     // e = exp2(g - cK2)
            e0.x = exp2fast(fmaf(cc0.x, NEG_K2, g0.x));
            e0.y = exp2fast(fmaf(cc0.y, NEG_K2, g0.y));
            e0.z = exp2fast(fmaf(cc0.z, NEG_K2, g0.z));
            e0.w = exp2fast(fmaf(cc0.w, NEG_K2, g0.w));
            e1.x = exp2fast(fmaf(cc1.x, NEG_K2, g1.x));
            e1.y = exp2fast(fmaf(cc1.y, NEG_K2, g1.y));
            e1.z = exp2fast(fmaf(cc1.z, NEG_K2, g1.z));
            e1.w = exp2fast(fmaf(cc1.w, NEG_K2, g1.w));

            float s = ((e0.x + e0.y) + (e0.z + e0.w))
                    + ((e1.x + e1.y) + (e1.z + e1.w));
            #pragma unroll
            for (int o = 32; o > 0; o >>= 1) s += __shfl_xor(s, o, 64);

            const int   m  = m0 + wave * 8 + r;
            const float ts = amarg[b * MM + m] * rcpfast(s);  // = exp2(F_m)

            if (!lastIt) {
                ca0.x = fmaf(ts * e0.x, iv0.x, ca0.x);
                ca0.y = fmaf(ts * e0.y, iv0.y, ca0.y);
                ca0.z = fmaf(ts * e0.z, iv0.z, ca0.z);
                ca0.w = fmaf(ts * e0.w, iv0.w, ca0.w);
                ca1.x = fmaf(ts * e1.x, iv1.x, ca1.x);
                ca1.y = fmaf(ts * e1.y, iv1.y, ca1.y);
                ca1.z = fmaf(ts * e1.z, iv1.z, ca1.z);
                ca1.w = fmaf(ts * e1.w, iv1.w, ca1.w);
            } else {                            // p = exp2(F_m)*e
                float4 o0, o1;
                o0.x = ts * e0.x; o0.y = ts * e0.y;
                o0.z = ts * e0.z; o0.w = ts * e0.w;
                o1.x = ts * e1.x; o1.y = ts * e1.y;
                o1.z = ts * e1.z; o1.w = ts * e1.w;
                float* op = out + (size_t)b * MM * NN + (size_t)m * NN + lane * 4;
                *(float4*)op         = o0;
                *(float4*)(op + 256) = o1;
            }
            cc0 = cn0; cc1 = cn1;
        }

        if (!lastIt) {
            *(float4*)&sPartial[wave][lane * 4]       = ca0;
            *(float4*)&sPartial[wave][lane * 4 + 256] = ca1;
            __syncthreads();
            float p8 = 0.f;
            #pragma unroll
            for (int w = 0; w < SLICES; ++w) p8 += sPartial[w][t];
            st_coh(&cpB[slice * NN + t], p8);
            target += SLICES;
            batch_barrier(bc, target);
        }
    }
}

// ============================================================================
// Fallback (proven round-1/6 path, 40 dispatches) if ws is too small.
// ============================================================================
__device__ __forceinline__ float block_max512(float v, float* sRed) {
    const int t = threadIdx.x;
    float wm = v;
    #pragma unroll
    for (int o = 32; o > 0; o >>= 1) wm = fmaxf(wm, __shfl_xor(wm, o, 64));
    if ((t & 63) == 0) sRed[t >> 6] = wm;
    __syncthreads();
    if (t == 0) {
        float m2 = sRed[0];
        #pragma unroll
        for (int i = 1; i < 8; ++i) m2 = fmaxf(m2, sRed[i]);
        sRed[0] = m2;
    }
    __syncthreads();
    const float r = sRed[0];
    __syncthreads();
    return r;
}

__global__ __launch_bounds__(512) void col_kernel(
    const float* __restrict__ c, const float* __restrict__ bmarg,
    const float* __restrict__ F, float* __restrict__ G, int first)
{
    __shared__ float sF[MM];
    __shared__ float sPart[16][128];
    __shared__ float sRed[8];

    const int b  = blockIdx.x >> 2;
    const int n0 = (blockIdx.x & 3) * 128;
    const int t  = threadIdx.x;

    float maxF = 0.0f, v = 0.0f;
    if (!first) {
        v = F[b * MM + t];
        maxF = block_max512(v, sRed);
    }
    sF[t] = v - maxF;
    __syncthreads();

    const int lane_c = t & 31;
    const int mg     = t >> 5;
    const int n4     = n0 + lane_c * 4;
    const float* cp  = c + (size_t)b * MM * NN;
    const int m0     = mg * 32;

    float s0 = 0.f, s1 = 0.f, s2 = 0.f, s3 = 0.f;
    #pragma unroll 4
    for (int r = 0; r < 32; ++r) {
        const int m = m0 + r;
        const float fp = sF[m];
        const float4 cv = *(const float4*)(cp + (size_t)m * NN + n4);
        s0 += exp2fast(fmaf(cv.x, NEG_K2, fp));
        s1 += exp2fast(fmaf(cv.y, NEG_K2, fp));
        s2 += exp2fast(fmaf(cv.z, NEG_K2, fp));
        s3 += exp2fast(fmaf(cv.w, NEG_K2, fp));
    }
    sPart[mg][lane_c * 4 + 0] = s0;
    sPart[mg][lane_c * 4 + 1] = s1;
    sPart[mg][lane_c * 4 + 2] = s2;
    sPart[mg][lane_c * 4 + 3] = s3;
    __syncthreads();

    if (t < 128) {
        float tot = 0.f;
        #pragma unroll
        for (int g = 0; g < 16; ++g) tot += sPart[g][t];
        const int n = n0 + t;
        G[b * NN + n] = log2fast(bmarg[b * NN + n]) - maxF - log2fast(tot);
    }
}

template <bool WRITE_OUT>
__global__ __launch_bounds__(512) void row_kernel(
    const float* __restrict__ c, const float* __restrict__ amarg,
    const float* __restrict__ G, float* __restrict__ F, float* __restrict__ out)
{
    __shared__ float sG2[NN];
    __shared__ float sRed[8];

    const int b  = blockIdx.x >> 3;
    const int m0 = (blockIdx.x & 7) * 64;
    const int t  = threadIdx.x;

    const float v    = G[b * NN + t];
    const float maxG = block_max512(v, sRed);
    sG2[t] = v - maxG;
    __syncthreads();

    const int wave = t >> 6;
    const int lane = t & 63;
    const float* cp = c + (size_t)b * MM * NN;

    const float4 g0 = *(const float4*)&sG2[lane * 4];
    const float4 g1 = *(const float4*)&sG2[lane * 4 + 256];

    #pragma unroll 2
    for (int r = 0; r < 8; ++r) {
        const int m = m0 + wave * 8 + r;
        const float* rowp = cp + (size_t)m * NN;
        const float4 c0 = *(const float4*)(rowp + lane * 4);
        const float4 c1 = *(const float4*)(rowp + lane * 4 + 256);

        float s = exp2fast(fmaf(c0.x, NEG_K2, g0.x)) + exp2fast(fmaf(c0.y, NEG_K2, g0.y))
                + exp2fast(fmaf(c0.z, NEG_K2, g0.z)) + exp2fast(fmaf(c0.w, NEG_K2, g0.w))
                + exp2fast(fmaf(c1.x, NEG_K2, g1.x)) + exp2fast(fmaf(c1.y, NEG_K2, g1.y))
                + exp2fast(fmaf(c1.z, NEG_K2, g1.z)) + exp2fast(fmaf(c1.w, NEG_K2, g1.w));
        #pragma unroll
        for (int o = 32; o > 0; o >>= 1) s += __shfl_xor(s, o, 64);

        const float Fm = log2fast(amarg[b * MM + m]) - maxG - log2fast(s);
        if (lane == 0) F[b * MM + m] = Fm;

        if (WRITE_OUT) {
            const float base = Fm + maxG;
            float4 o0, o1;
            o0.x = exp2fast(fmaf(c0.x, NEG_K2, base + g0.x));
            o0.y = exp2fast(fmaf(c0.y, NEG_K2, base + g0.y));
            o0.z = exp2fast(fmaf(c0.z, NEG_K2, base + g0.z));
            o0.w = exp2fast(fmaf(c0.w, NEG_K2, base + g0.w));
            o1.x = exp2fast(fmaf(c1.x, NEG_K2, base + g1.x));
            o1.y = exp2fast(fmaf(c1.y, NEG_K2, base + g1.y));
            o1.z = exp2fast(fmaf(c1.z, NEG_K2, base + g1.z));
            o1.w = exp2fast(fmaf(c1.w, NEG_K2, base + g1.w));
            float* op = out + (size_t)b * MM * NN + (size_t)m * NN;
            *(float4*)(op + lane * 4)       = o0;
            *(float4*)(op + lane * 4 + 256) = o1;
        }
    }
}

extern "C" void kernel_launch(void* const* d_in, const int* in_sizes, int n_in,
                              void* d_out, int out_size, void* d_ws, size_t ws_size,
                              hipStream_t stream) {
    const float* c  = (const float*)d_in[0];
    const float* am = (const float*)d_in[1];
    const float* bm = (const float*)d_in[2];
    float* out = (float*)d_out;

    // primary layout: colPart[BB][SLICES][NN] (8 MB) + ctr[BB]
    float*    colPart = (float*)d_ws;
    unsigned* ctr     = (unsigned*)(colPart + (size_t)BB * SLICES * NN);
    const size_t need = (size_t)BB * SLICES * NN * sizeof(float)
                      + (size_t)BB * sizeof(unsigned);

    if (ws_size >= need) {
        hipMemsetAsync(ctr, 0, BB * sizeof(unsigned), stream);
        hipLaunchKernelGGL(sink_fused, dim3(BB * SLICES), dim3(512), 0, stream,
                           c, am, bm, out, colPart, ctr);
    } else {
        // fallback: 40-dispatch proven path (needs only 256 KB: F + G)
        float* F = (float*)d_ws;
        float* G = F + BB * MM;
        for (int it = 0; it < NUM_SINK; ++it) {
            hipLaunchKernelGGL(col_kernel, dim3(BB * 4), dim3(512), 0, stream,
                               c, bm, F, G, it == 0 ? 1 : 0);
            if (it < NUM_SINK - 1)
                hipLaunchKernelGGL(row_kernel<false>, dim3(BB * 8), dim3(512), 0, stream,
                                   c, am, G, F, out);
            else
                hipLaunchKernelGGL(row_kernel<true>, dim3(BB * 8), dim3(512), 0, stream,
                                   c, am, G, F, out);
        }
    }
}